// Round 1
// baseline (1239.951 us; speedup 1.0000x reference)
//
#include <hip/hip_runtime.h>

#define B_ 8
#define N_ 8192
#define C_ 256
#define L_ 4
#define E_ 131072
#define BN_ 65536        // B_*N_
#define EDGES_ 1048576   // B_*E_

typedef __attribute__((ext_vector_type(8))) short short8;
typedef __attribute__((ext_vector_type(4))) float f32x4;

__device__ __forceinline__ unsigned short f2bf(float f){
  unsigned int u = __builtin_bit_cast(unsigned int, f);
  u += 0x7fffu + ((u >> 16) & 1u);
  return (unsigned short)(u >> 16);
}
__device__ __forceinline__ float bf2f(unsigned short h){
  unsigned int u = ((unsigned int)h) << 16;
  return __builtin_bit_cast(float, u);
}

// ---------------- f32 -> bf16 convert (x4 vectorized) ----------------
__launch_bounds__(256)
__global__ void cvt_bf16_k(const float* __restrict__ in, unsigned short* __restrict__ out, int n4){
  int t = blockIdx.x * 256 + threadIdx.x;
  if (t >= n4) return;
  float4 v = ((const float4*)in)[t];
  ushort4 o;
  o.x = f2bf(v.x); o.y = f2bf(v.y); o.z = f2bf(v.z); o.w = f2bf(v.w);
  ((ushort4*)out)[t] = o;
}

// ---------------- CSR build (counting sort by dst) ----------------
__launch_bounds__(256)
__global__ void hist_k(const int* __restrict__ ei, int* __restrict__ cnt){
  int t = blockIdx.x * 256 + threadIdx.x;
  int b = t >> 17, e = t & (E_ - 1);
  int dst = ei[b * (2 * E_) + E_ + e];
  atomicAdd(&cnt[(b << 13) + dst], 1);
}

__launch_bounds__(256)
__global__ void scan_k(const int* __restrict__ cnt, int* __restrict__ row_ptr, int* __restrict__ cursor){
  __shared__ int lsum[256];
  int t = threadIdx.x;
  int base = t << 8;
  int s = 0;
  for (int i = 0; i < 256; ++i) s += cnt[base + i];
  lsum[t] = s;
  __syncthreads();
  for (int d = 1; d < 256; d <<= 1){
    int v = (t >= d) ? lsum[t - d] : 0;
    __syncthreads();
    lsum[t] += v;
    __syncthreads();
  }
  int off = lsum[t] - s;   // exclusive prefix of this 256-chunk
  for (int i = 0; i < 256; ++i){
    row_ptr[base + i] = off;
    cursor[base + i]  = off;
    off += cnt[base + i];
  }
  if (t == 255) row_ptr[BN_] = off;
}

__launch_bounds__(256)
__global__ void scat_k(const int* __restrict__ ei, int* __restrict__ cursor, int* __restrict__ col){
  int t = blockIdx.x * 256 + threadIdx.x;
  int b = t >> 17, e = t & (E_ - 1);
  int src = ei[b * (2 * E_) + e];
  int dst = ei[b * (2 * E_) + E_ + e];
  int pos = atomicAdd(&cursor[(b << 13) + dst], 1);
  col[pos] = (b << 13) + src;
}

// ---- aggregation: one wave per dst node, CSR, bf16 gather, f32 accum ----
// blockIdx%8 = graph id -> pins each graph's 4 MiB bf16 table to one XCD's L2.
__launch_bounds__(256)
__global__ void agg_k(const unsigned short* __restrict__ feat, const int* __restrict__ row_ptr,
                      const int* __restrict__ col, unsigned short* __restrict__ out){
  int w = threadIdx.x >> 6, lane = threadIdx.x & 63;
  int g = blockIdx.x & 7, sblk = blockIdx.x >> 3;
  int node = (g << 13) + (sblk << 2) + w;
  int beg = row_ptr[node], end = row_ptr[node + 1];
  int ch = lane << 2;  // 4 channels per lane
  float a0=0,a1=0,a2=0,a3=0,b0=0,b1=0,b2=0,b3=0;
  int e = beg;
  for (; e + 2 <= end; e += 2){
    int s0 = col[e], s1 = col[e + 1];
    ushort4 v0 = *(const ushort4*)(feat + ((size_t)s0 << 8) + ch);
    ushort4 v1 = *(const ushort4*)(feat + ((size_t)s1 << 8) + ch);
    a0 += bf2f(v0.x); a1 += bf2f(v0.y); a2 += bf2f(v0.z); a3 += bf2f(v0.w);
    b0 += bf2f(v1.x); b1 += bf2f(v1.y); b2 += bf2f(v1.z); b3 += bf2f(v1.w);
  }
  if (e < end){
    int s0 = col[e];
    ushort4 v0 = *(const ushort4*)(feat + ((size_t)s0 << 8) + ch);
    a0 += bf2f(v0.x); a1 += bf2f(v0.y); a2 += bf2f(v0.z); a3 += bf2f(v0.w);
  }
  ushort4 o;
  o.x = f2bf(a0 + b0); o.y = f2bf(a1 + b1); o.z = f2bf(a2 + b2); o.w = f2bf(a3 + b3);
  *(ushort4*)(out + ((size_t)node << 8) + ch) = o;
}

// ---------------- multi-operand GEMM: out = relu(sum_p A_p @ W_p.T + b) ----------------
// A_p: [65536, 256] bf16 row-major. W_p: [256, K] rows at stride ldw (B^T layout).
// 128x128 tile, 4 waves (2x2), 16x16x32 bf16 MFMA, global_load_lds width-16 staging.
#define GLDS16(gp, lp) __builtin_amdgcn_global_load_lds( \
    (const __attribute__((address_space(1))) void*)(gp), \
    (__attribute__((address_space(3))) void*)(lp), 16, 0, 0)

template<int P>
__launch_bounds__(256)
__global__ void gemm_k(const unsigned short* __restrict__ A0, const unsigned short* __restrict__ A1,
                       const unsigned short* __restrict__ A2, const unsigned short* __restrict__ A3,
                       const unsigned short* __restrict__ W0, const unsigned short* __restrict__ W1,
                       const unsigned short* __restrict__ W2, const unsigned short* __restrict__ W3,
                       int ldw, const float* __restrict__ bias,
                       unsigned short* __restrict__ outb, float* __restrict__ outf){
  __shared__ unsigned short a_t[128 * 32];
  __shared__ unsigned short b_t[128 * 32];
  const unsigned short* As[4] = {A0, A1, A2, A3};
  const unsigned short* Ws[4] = {W0, W1, W2, W3};
  const int tn = blockIdx.x & 1, tm = blockIdx.x >> 1;
  const int m0 = tm << 7, n0 = tn << 7;
  const int t = threadIdx.x, lane = t & 63;
  const int w = t >> 6, wr = w >> 1, wc = w & 1;
  const int lrow = lane & 15, kg = lane >> 4;
  f32x4 acc[4][4] = {};
#pragma unroll
  for (int p = 0; p < P; ++p){
    const unsigned short* A = As[p] + (size_t)m0 * C_;
    const unsigned short* W = Ws[p] + (size_t)n0 * ldw;
    for (int k0 = 0; k0 < C_; k0 += 32){
      // stage 128x32 bf16 A-tile and W-tile (8 KiB each) via global_load_lds
#pragma unroll
      for (int c = t; c < 512; c += 256){
        int row = c >> 2, seg = c & 3;
        GLDS16(A + row * C_  + k0 + seg * 8, &a_t[c * 8]);
        GLDS16(W + row * ldw + k0 + seg * 8, &b_t[c * 8]);
      }
      __syncthreads();
      short8 af[4], bfr[4];
#pragma unroll
      for (int m = 0; m < 4; ++m)
        af[m] = *(const short8*)&a_t[((wr << 6) + (m << 4) + lrow) * 32 + (kg << 3)];
#pragma unroll
      for (int n = 0; n < 4; ++n)
        bfr[n] = *(const short8*)&b_t[((wc << 6) + (n << 4) + lrow) * 32 + (kg << 3)];
#pragma unroll
      for (int m = 0; m < 4; ++m)
#pragma unroll
        for (int n = 0; n < 4; ++n)
          acc[m][n] = __builtin_amdgcn_mfma_f32_16x16x32_bf16(af[m], bfr[n], acc[m][n], 0, 0, 0);
      __syncthreads();
    }
  }
  // epilogue: + bias, relu, store bf16 (and f32 when requested)
#pragma unroll
  for (int n = 0; n < 4; ++n){
    int colg = n0 + (wc << 6) + (n << 4) + lrow;
    float bv = bias[colg];
#pragma unroll
    for (int m = 0; m < 4; ++m){
      int rbase = m0 + (wr << 6) + (m << 4) + (kg << 2);
#pragma unroll
      for (int j = 0; j < 4; ++j){
        float v = acc[m][n][j] + bv;
        v = v > 0.f ? v : 0.f;
        size_t idx = (size_t)(rbase + j) * C_ + colg;
        outb[idx] = f2bf(v);
        if (outf) outf[idx] = v;
      }
    }
  }
}

// ---------------------------------------------------------------------------
extern "C" void kernel_launch(void* const* d_in, const int* in_sizes, int n_in,
                              void* d_out, int out_size, void* d_ws, size_t ws_size,
                              hipStream_t stream){
  const float* x_f   = (const float*)d_in[0];
  const float* bWr_f = (const float*)d_in[1];
  const float* bWn_f = (const float*)d_in[2];
  const float* bB    = (const float*)d_in[3];
  const float* aWr_f = (const float*)d_in[4];
  const float* aWn_f = (const float*)d_in[5];
  const float* aB    = (const float*)d_in[6];
  const int*   ei    = (const int*)d_in[7];
  float* out = (float*)d_out;
  (void)in_sizes; (void)n_in; (void)out_size; (void)ws_size;

  char* p = (char*)d_ws;
  const size_t BUF = (size_t)BN_ * C_ * sizeof(unsigned short); // 32 MiB
  auto alloc = [&](size_t bytes){ void* r = (void*)p; p += (bytes + 255) & ~(size_t)255; return r; };
  unsigned short* xb   = (unsigned short*)alloc(BUF);
  unsigned short* latA = (unsigned short*)alloc(BUF);
  unsigned short* latB = (unsigned short*)alloc(BUF);
  unsigned short* curA = (unsigned short*)alloc(BUF);
  unsigned short* curB = (unsigned short*)alloc(BUF);
  unsigned short* agg0 = (unsigned short*)alloc(BUF);
  unsigned short* agg1 = (unsigned short*)alloc(BUF);
  unsigned short* wbR  = (unsigned short*)alloc((size_t)L_ * C_ * C_ * 2);
  unsigned short* wbN  = (unsigned short*)alloc((size_t)L_ * C_ * C_ * 2);
  unsigned short* waR  = (unsigned short*)alloc((size_t)L_ * C_ * 2 * C_ * 2);
  unsigned short* waN  = (unsigned short*)alloc((size_t)L_ * C_ * 2 * C_ * 2);
  int* cnt     = (int*)alloc((size_t)BN_ * 4);
  int* row_ptr = (int*)alloc((size_t)(BN_ + 1) * 4);
  int* cursor  = (int*)alloc((size_t)BN_ * 4);
  int* colx    = (int*)alloc((size_t)EDGES_ * 4);

  // bf16 conversions
  cvt_bf16_k<<<BN_ * C_ / 4 / 256, 256, 0, stream>>>(x_f, xb, BN_ * C_ / 4);
  cvt_bf16_k<<<L_ * C_ * C_ / 4 / 256, 256, 0, stream>>>(bWr_f, wbR, L_ * C_ * C_ / 4);
  cvt_bf16_k<<<L_ * C_ * C_ / 4 / 256, 256, 0, stream>>>(bWn_f, wbN, L_ * C_ * C_ / 4);
  cvt_bf16_k<<<L_ * C_ * 2 * C_ / 4 / 256, 256, 0, stream>>>(aWr_f, waR, L_ * C_ * 2 * C_ / 4);
  cvt_bf16_k<<<L_ * C_ * 2 * C_ / 4 / 256, 256, 0, stream>>>(aWn_f, waN, L_ * C_ * 2 * C_ / 4);

  // CSR build
  hipMemsetAsync(cnt, 0, (size_t)BN_ * 4, stream);
  hist_k<<<EDGES_ / 256, 256, 0, stream>>>(ei, cnt);
  scan_k<<<1, 256, 0, stream>>>(cnt, row_ptr, cursor);
  scat_k<<<EDGES_ / 256, 256, 0, stream>>>(ei, cursor, colx);

  const int AGG_GRID  = BN_ / 4;                 // 16384 blocks, 4 waves/block
  const int GEMM_GRID = (BN_ / 128) * (C_ / 128); // 1024

  const size_t WB = (size_t)C_ * C_;       // base per-layer weight elems
  const size_t WA = (size_t)C_ * 2 * C_;   // adapter per-layer weight elems

  // base layer 0: lat1 = relu(x@Wr0.T + agg(x)@Wn0.T + b0)
  agg_k<<<AGG_GRID, 256, 0, stream>>>(xb, row_ptr, colx, agg0);                 // agg(x)
  gemm_k<2><<<GEMM_GRID, 256, 0, stream>>>(xb, agg0, nullptr, nullptr,
      wbR, wbN, nullptr, nullptr, C_, bB, latA, nullptr);                        // lat1
  // base layer 1
  agg_k<<<AGG_GRID, 256, 0, stream>>>(latA, row_ptr, colx, agg1);               // agg(lat1)
  gemm_k<2><<<GEMM_GRID, 256, 0, stream>>>(latA, agg1, nullptr, nullptr,
      wbR + WB, wbN + WB, nullptr, nullptr, C_, bB + 256, latB, nullptr);        // lat2
  // adapter layer 0: concat(lat1, x)
  gemm_k<4><<<GEMM_GRID, 256, 0, stream>>>(latA, xb, agg1, agg0,
      waR, waR + 256, waN, waN + 256, 2 * C_, aB, curA, nullptr);                // curr1
  // aggs for next pair
  agg_k<<<AGG_GRID, 256, 0, stream>>>(curA, row_ptr, colx, agg0);               // agg(curr1)
  agg_k<<<AGG_GRID, 256, 0, stream>>>(latB, row_ptr, colx, agg1);               // agg(lat2)
  // base layer 2
  gemm_k<2><<<GEMM_GRID, 256, 0, stream>>>(latB, agg1, nullptr, nullptr,
      wbR + 2 * WB, wbN + 2 * WB, nullptr, nullptr, C_, bB + 512, latA, nullptr); // lat3
  // adapter layer 1: concat(lat2, curr1)
  gemm_k<4><<<GEMM_GRID, 256, 0, stream>>>(latB, curA, agg1, agg0,
      waR + WA, waR + WA + 256, waN + WA, waN + WA + 256, 2 * C_, aB + 256, curB, nullptr); // curr2
  agg_k<<<AGG_GRID, 256, 0, stream>>>(curB, row_ptr, colx, agg0);               // agg(curr2)
  agg_k<<<AGG_GRID, 256, 0, stream>>>(latA, row_ptr, colx, agg1);               // agg(lat3)
  // base layer 3 -> d_out first half (f32)
  gemm_k<2><<<GEMM_GRID, 256, 0, stream>>>(latA, agg1, nullptr, nullptr,
      wbR + 3 * WB, wbN + 3 * WB, nullptr, nullptr, C_, bB + 768, latB, out);    // lat4
  // adapter layer 2: concat(lat3, curr2)
  gemm_k<4><<<GEMM_GRID, 256, 0, stream>>>(latA, curB, agg1, agg0,
      waR + 2 * WA, waR + 2 * WA + 256, waN + 2 * WA, waN + 2 * WA + 256, 2 * C_, aB + 512, curA, nullptr); // curr3
  agg_k<<<AGG_GRID, 256, 0, stream>>>(curA, row_ptr, colx, agg0);               // agg(curr3)
  agg_k<<<AGG_GRID, 256, 0, stream>>>(latB, row_ptr, colx, agg1);               // agg(lat4)
  // adapter layer 3 -> d_out second half (f32)
  gemm_k<4><<<GEMM_GRID, 256, 0, stream>>>(latB, curA, agg1, agg0,
      waR + 3 * WA, waR + 3 * WA + 256, waN + 3 * WA, waN + 3 * WA + 256, 2 * C_, aB + 768,
      curB, out + (size_t)BN_ * C_);
}